// Round 1
// baseline (398.034 us; speedup 1.0000x reference)
//
#include <hip/hip_runtime.h>
#include <stdint.h>

#define S 4096
#define BB 4
#define F 512
#define D 64
#define NROW (BB * S)   // 16384

typedef float f32x4 __attribute__((ext_vector_type(4)));
typedef short s16x8 __attribute__((ext_vector_type(8)));

__device__ __forceinline__ unsigned short f2bf(float f) {
    union { float f; uint32_t u; } v; v.f = f;
    uint32_t u = v.u;
    return (unsigned short)((u + 0x7FFFu + ((u >> 16) & 1u)) >> 16);  // RNE
}
__device__ __forceinline__ float bf2f(unsigned short h) {
    union { float f; uint32_t u; } v; v.u = ((uint32_t)h) << 16;
    return v.f;
}

// ---------------------------------------------------------------------------
// Kernel 0a: split features -> bf16 hi/lo, and compute charge = sigmoid(f.wc+b)
// grid 4096 x 256 (4 waves/block, 1 row per wave)
// ---------------------------------------------------------------------------
__global__ __launch_bounds__(256) void k_split(
        const float* __restrict__ feat, const float* __restrict__ wc,
        const float* __restrict__ bc,
        unsigned short* __restrict__ fH, unsigned short* __restrict__ fL,
        float* __restrict__ charge) {
    int wave = threadIdx.x >> 6, lane = threadIdx.x & 63;
    int row = blockIdx.x * 4 + wave;
    const float* fr = feat + (size_t)row * F + lane * 8;
    f32x4 a = *(const f32x4*)fr;
    f32x4 b = *(const f32x4*)(fr + 4);
    const float* wr = wc + lane * 8;
    f32x4 wa = *(const f32x4*)wr;
    f32x4 wb = *(const f32x4*)(wr + 4);
    float p = a.x*wa.x + a.y*wa.y + a.z*wa.z + a.w*wa.w
            + b.x*wb.x + b.y*wb.y + b.z*wb.z + b.w*wb.w;
    #pragma unroll
    for (int o = 32; o; o >>= 1) p += __shfl_xor(p, o);

    float vals[8] = {a.x, a.y, a.z, a.w, b.x, b.y, b.z, b.w};
    unsigned short h[8], l[8];
    #pragma unroll
    for (int m = 0; m < 8; m++) {
        h[m] = f2bf(vals[m]);
        l[m] = f2bf(vals[m] - bf2f(h[m]));
    }
    *(uint4*)(fH + (size_t)row * F + lane * 8) = *(const uint4*)h;
    *(uint4*)(fL + (size_t)row * F + lane * 8) = *(const uint4*)l;
    if (lane == 0) charge[row] = 1.f / (1.f + expf(-(p + bc[0])));
}

// ---------------------------------------------------------------------------
// Kernel 0b: W -> transposed bf16 hi/lo  Wt[c][k] (c: 0..63 Wq, 64..127 Wk)
// grid 64 x 256
// ---------------------------------------------------------------------------
__global__ __launch_bounds__(256) void k_wt(
        const float* __restrict__ Wq, const float* __restrict__ Wk,
        unsigned short* __restrict__ wtH, unsigned short* __restrict__ wtL) {
    int t = blockIdx.x * 256 + threadIdx.x;   // 16384 threads
    int c = t >> 7;                            // 0..127
    int k0 = (t & 127) * 4;                    // 0..508
    const float* src = (c < 64) ? (Wq + c) : (Wk + (c - 64));
    unsigned short h[4], l[4];
    #pragma unroll
    for (int j = 0; j < 4; j++) {
        float v = src[(size_t)(k0 + j) * D];
        h[j] = f2bf(v);
        l[j] = f2bf(v - bf2f(h[j]));
    }
    *(uint2*)(wtH + (size_t)c * F + k0) = *(const uint2*)h;
    *(uint2*)(wtL + (size_t)c * F + k0) = *(const uint2*)l;
}

// ---------------------------------------------------------------------------
// Kernel 1: Q/K = feat @ W via bf16x3 MFMA; fold charge & -ls/8; split hi/lo.
// grid 256 x 256 (4 waves, each wave: 16 rows x 128 cols, K=512)
// ---------------------------------------------------------------------------
__global__ __launch_bounds__(256) void k_qk(
        const unsigned short* __restrict__ fH, const unsigned short* __restrict__ fL,
        const unsigned short* __restrict__ wtH, const unsigned short* __restrict__ wtL,
        const float* __restrict__ charge, const float* __restrict__ lsp,
        unsigned short* __restrict__ qH, unsigned short* __restrict__ qL,
        unsigned short* __restrict__ kH, unsigned short* __restrict__ kL) {
    int wave = threadIdx.x >> 6, lane = threadIdx.x & 63;
    int col = lane & 15, kg = lane >> 4;
    int row0 = blockIdx.x * 64 + wave * 16;

    f32x4 acc[8];
    #pragma unroll
    for (int j = 0; j < 8; j++) acc[j] = (f32x4)0.f;

    size_t aoff = (size_t)(row0 + col) * F + kg * 8;
    for (int ks = 0; ks < 16; ks++) {
        s16x8 ah = *(const s16x8*)(fH + aoff + ks * 32);
        s16x8 al = *(const s16x8*)(fL + aoff + ks * 32);
        #pragma unroll
        for (int ju = 0; ju < 8; ju++) {
            size_t boff = (size_t)(ju * 16 + col) * F + ks * 32 + kg * 8;
            s16x8 bh = *(const s16x8*)(wtH + boff);
            s16x8 bl = *(const s16x8*)(wtL + boff);
            acc[ju] = __builtin_amdgcn_mfma_f32_16x16x32_bf16(ah, bh, acc[ju], 0, 0, 0);
            acc[ju] = __builtin_amdgcn_mfma_f32_16x16x32_bf16(ah, bl, acc[ju], 0, 0, 0);
            acc[ju] = __builtin_amdgcn_mfma_f32_16x16x32_bf16(al, bh, acc[ju], 0, 0, 0);
        }
    }

    float ls = lsp[0];
    #pragma unroll
    for (int ju = 0; ju < 8; ju++) {
        int c = ju * 16 + col;
        #pragma unroll
        for (int r = 0; r < 4; r++) {
            int row = row0 + kg * 4 + r;
            float ch = charge[row];
            float v = acc[ju][r];
            float sc;
            unsigned short *dh, *dl;
            if (c < 64) { sc = -0.125f * ls * ch; dh = qH; dl = qL; }
            else        { sc = ch;               dh = kH; dl = kL; }
            int cc = c & 63;
            float q = v * sc;
            unsigned short hh = f2bf(q);
            unsigned short ll = f2bf(q - bf2f(hh));
            dh[(size_t)row * D + cc] = hh;
            dl[(size_t)row * D + cc] = ll;
        }
    }
}

// ---------------------------------------------------------------------------
// Kernel 2: energy[b,i,j] = (Qc_i . Kc_j) / max(|i-j|,1)
// grid (64 jt, 32 it, 4 b) x 256; wave: 32 i x 64 j
// ---------------------------------------------------------------------------
__global__ __launch_bounds__(256) void k_energy(
        const unsigned short* __restrict__ qH, const unsigned short* __restrict__ qL,
        const unsigned short* __restrict__ kH, const unsigned short* __restrict__ kL,
        float* __restrict__ out) {
    int wave = threadIdx.x >> 6, lane = threadIdx.x & 63;
    int col = lane & 15, kg = lane >> 4;
    int jt = blockIdx.x, it = blockIdx.y, b = blockIdx.z;
    int i0 = it * 128 + wave * 32;
    int j0 = jt * 64;
    size_t base = (size_t)b * S;

    s16x8 qfh[2][2], qfl[2][2];
    #pragma unroll
    for (int iu = 0; iu < 2; iu++) {
        size_t ro = (base + i0 + iu * 16 + col) * D + kg * 8;
        #pragma unroll
        for (int kh2 = 0; kh2 < 2; kh2++) {
            qfh[iu][kh2] = *(const s16x8*)(qH + ro + kh2 * 32);
            qfl[iu][kh2] = *(const s16x8*)(qL + ro + kh2 * 32);
        }
    }

    f32x4 acc[2][4];
    #pragma unroll
    for (int iu = 0; iu < 2; iu++)
        #pragma unroll
        for (int ju = 0; ju < 4; ju++) acc[iu][ju] = (f32x4)0.f;

    #pragma unroll
    for (int ju = 0; ju < 4; ju++) {
        size_t ro = (base + j0 + ju * 16 + col) * D + kg * 8;
        s16x8 kf0 = *(const s16x8*)(kH + ro);
        s16x8 kf1 = *(const s16x8*)(kH + ro + 32);
        s16x8 kg0 = *(const s16x8*)(kL + ro);
        s16x8 kg1 = *(const s16x8*)(kL + ro + 32);
        #pragma unroll
        for (int iu = 0; iu < 2; iu++) {
            f32x4 a = acc[iu][ju];
            a = __builtin_amdgcn_mfma_f32_16x16x32_bf16(qfh[iu][0], kf0, a, 0, 0, 0);
            a = __builtin_amdgcn_mfma_f32_16x16x32_bf16(qfh[iu][1], kf1, a, 0, 0, 0);
            a = __builtin_amdgcn_mfma_f32_16x16x32_bf16(qfh[iu][0], kg0, a, 0, 0, 0);
            a = __builtin_amdgcn_mfma_f32_16x16x32_bf16(qfh[iu][1], kg1, a, 0, 0, 0);
            a = __builtin_amdgcn_mfma_f32_16x16x32_bf16(qfl[iu][0], kf0, a, 0, 0, 0);
            a = __builtin_amdgcn_mfma_f32_16x16x32_bf16(qfl[iu][1], kf1, a, 0, 0, 0);
            acc[iu][ju] = a;
        }
    }

    #pragma unroll
    for (int iu = 0; iu < 2; iu++)
        #pragma unroll
        for (int ju = 0; ju < 4; ju++)
            #pragma unroll
            for (int r = 0; r < 4; r++) {
                int i = i0 + iu * 16 + kg * 4 + r;
                int j = j0 + ju * 16 + col;
                float dist = fmaxf(fabsf((float)(i - j)), 1.0f);
                out[(base + i) * (size_t)S + j] =
                    acc[iu][ju][r] * __builtin_amdgcn_rcpf(dist);
            }
}

// ---------------------------------------------------------------------------
extern "C" void kernel_launch(void* const* d_in, const int* in_sizes, int n_in,
                              void* d_out, int out_size, void* d_ws, size_t ws_size,
                              hipStream_t stream) {
    const float* feat = (const float*)d_in[0];
    const float* Wq   = (const float*)d_in[1];
    const float* Wk   = (const float*)d_in[2];
    const float* wc   = (const float*)d_in[3];
    const float* bc   = (const float*)d_in[4];
    const float* ls   = (const float*)d_in[5];
    float* out = (float*)d_out;

    char* ws = (char*)d_ws;
    unsigned short* fH  = (unsigned short*)ws;                 ws += (size_t)NROW * F * 2;
    unsigned short* fL  = (unsigned short*)ws;                 ws += (size_t)NROW * F * 2;
    unsigned short* wtH = (unsigned short*)ws;                 ws += (size_t)128 * F * 2;
    unsigned short* wtL = (unsigned short*)ws;                 ws += (size_t)128 * F * 2;
    float*          chg = (float*)ws;                          ws += (size_t)NROW * 4;
    unsigned short* qH  = (unsigned short*)ws;                 ws += (size_t)NROW * D * 2;
    unsigned short* qL  = (unsigned short*)ws;                 ws += (size_t)NROW * D * 2;
    unsigned short* kH  = (unsigned short*)ws;                 ws += (size_t)NROW * D * 2;
    unsigned short* kL  = (unsigned short*)ws;                 ws += (size_t)NROW * D * 2;

    hipLaunchKernelGGL(k_split, dim3(NROW / 4), dim3(256), 0, stream,
                       feat, wc, bc, fH, fL, chg);
    hipLaunchKernelGGL(k_wt, dim3(64), dim3(256), 0, stream, Wq, Wk, wtH, wtL);
    hipLaunchKernelGGL(k_qk, dim3(NROW / 64), dim3(256), 0, stream,
                       fH, fL, wtH, wtL, chg, ls, qH, qL, kH, kL);
    hipLaunchKernelGGL(k_energy, dim3(S / 64, S / 128, BB), dim3(256), 0, stream,
                       qH, qL, kH, kL, out);
}

// Round 3
// 393.450 us; speedup vs baseline: 1.0117x; 1.0117x over previous
//
#include <hip/hip_runtime.h>
#include <stdint.h>

#define S 4096
#define BB 4
#define F 512
#define D 64
#define NROW (BB * S)   // 16384

typedef float f32x4 __attribute__((ext_vector_type(4)));
typedef short s16x8 __attribute__((ext_vector_type(8)));

__device__ __forceinline__ unsigned short f2bf(float f) {
    union { float f; uint32_t u; } v; v.f = f;
    uint32_t u = v.u;
    return (unsigned short)((u + 0x7FFFu + ((u >> 16) & 1u)) >> 16);  // RNE
}
__device__ __forceinline__ float bf2f(unsigned short h) {
    union { float f; uint32_t u; } v; v.u = ((uint32_t)h) << 16;
    return v.f;
}

// ---------------------------------------------------------------------------
// Kernel 0: W -> transposed bf16 hi/lo  Wt[c][k] (c: 0..63 Wq, 64..127 Wk)
// grid 64 x 256
// ---------------------------------------------------------------------------
__global__ __launch_bounds__(256) void k_wt(
        const float* __restrict__ Wq, const float* __restrict__ Wk,
        unsigned short* __restrict__ wtH, unsigned short* __restrict__ wtL) {
    int t = blockIdx.x * 256 + threadIdx.x;   // 16384 threads
    int c = t >> 7;                            // 0..127
    int k0 = (t & 127) * 4;                    // 0..508
    const float* src = (c < 64) ? (Wq + c) : (Wk + (c - 64));
    unsigned short h[4], l[4];
    #pragma unroll
    for (int j = 0; j < 4; j++) {
        float v = src[(size_t)(k0 + j) * D];
        h[j] = f2bf(v);
        l[j] = f2bf(v - bf2f(h[j]));
    }
    *(uint2*)(wtH + (size_t)c * F + k0) = *(const uint2*)h;
    *(uint2*)(wtL + (size_t)c * F + k0) = *(const uint2*)l;
}

// ---------------------------------------------------------------------------
// Kernel 1 (fused): load feat fp32 -> bf16 hi/lo in regs, charge via in-wave
// reduce, MFMA vs Wt, fold charge & -ls/8 into Qc/Kc, store hi/lo.
// grid 1024 x 256: block = 16 rows; wave w covers cols w*32..w*32+31
// (waves 0,1 -> Q cols 0..63, waves 2,3 -> K cols 0..63). No LDS, no barriers.
// ---------------------------------------------------------------------------
__global__ __launch_bounds__(256) void k_qk2(
        const float* __restrict__ feat,
        const unsigned short* __restrict__ wtH, const unsigned short* __restrict__ wtL,
        const float* __restrict__ wc, const float* __restrict__ bc,
        const float* __restrict__ lsp,
        unsigned short* __restrict__ qH, unsigned short* __restrict__ qL,
        unsigned short* __restrict__ kH, unsigned short* __restrict__ kL) {
    int wave = threadIdx.x >> 6, lane = threadIdx.x & 63;
    int col = lane & 15, kg = lane >> 4;
    int row0 = blockIdx.x * 16;
    int c0 = wave * 32;

    f32x4 acc[2];
    acc[0] = (f32x4)0.f; acc[1] = (f32x4)0.f;
    float psum = 0.f;

    const float* arow = feat + (size_t)(row0 + col) * F + kg * 8;
    #pragma unroll 4
    for (int ks = 0; ks < 16; ks++) {
        f32x4 a0 = *(const f32x4*)(arow + ks * 32);
        f32x4 a1 = *(const f32x4*)(arow + ks * 32 + 4);
        const float* wr = wc + ks * 32 + kg * 8;
        f32x4 w0 = *(const f32x4*)wr;
        f32x4 w1 = *(const f32x4*)(wr + 4);
        psum += a0.x*w0.x + a0.y*w0.y + a0.z*w0.z + a0.w*w0.w
              + a1.x*w1.x + a1.y*w1.y + a1.z*w1.z + a1.w*w1.w;

        float vals[8] = {a0.x, a0.y, a0.z, a0.w, a1.x, a1.y, a1.z, a1.w};
        s16x8 ah, al;
        #pragma unroll
        for (int m = 0; m < 8; m++) {
            unsigned short hh = f2bf(vals[m]);
            ah[m] = (short)hh;
            al[m] = (short)f2bf(vals[m] - bf2f(hh));
        }
        #pragma unroll
        for (int ju = 0; ju < 2; ju++) {
            size_t boff = (size_t)(c0 + ju * 16 + col) * F + ks * 32 + kg * 8;
            s16x8 bh = *(const s16x8*)(wtH + boff);
            s16x8 bl = *(const s16x8*)(wtL + boff);
            acc[ju] = __builtin_amdgcn_mfma_f32_16x16x32_bf16(ah, bh, acc[ju], 0, 0, 0);
            acc[ju] = __builtin_amdgcn_mfma_f32_16x16x32_bf16(ah, bl, acc[ju], 0, 0, 0);
            acc[ju] = __builtin_amdgcn_mfma_f32_16x16x32_bf16(al, bh, acc[ju], 0, 0, 0);
        }
    }

    // charge for row (lane&15): combine kg groups (disjoint k slices)
    psum += __shfl_xor(psum, 16);
    psum += __shfl_xor(psum, 32);
    float sig = 1.f / (1.f + expf(-(psum + bc[0])));
    float ls = lsp[0];

    bool isQ = (c0 < 64);
    unsigned short* __restrict__ dh = isQ ? qH : kH;
    unsigned short* __restrict__ dl = isQ ? qL : kL;
    int ccb = (c0 & 63) + col;
    #pragma unroll
    for (int ju = 0; ju < 2; ju++) {
        #pragma unroll
        for (int r = 0; r < 4; r++) {
            int rl = kg * 4 + r;                 // local output row 0..15
            float ch = __shfl(sig, rl);          // charge[row0+rl]
            float sc = isQ ? (-0.125f * ls * ch) : ch;
            float v = acc[ju][r] * sc;
            unsigned short hh = f2bf(v);
            unsigned short ll = f2bf(v - bf2f(hh));
            size_t off = (size_t)(row0 + rl) * D + ccb + ju * 16;
            dh[off] = hh;
            dl[off] = ll;
        }
    }
}

// ---------------------------------------------------------------------------
// Kernel 2: energy[b,i,j] = (Qc_i . Kc_j) / max(|i-j|,1)
// Swapped MFMA operands: D[row=j][col=i] -> per-lane 4 consecutive j
// -> dwordx4 stores. Block tile 128i x 128j, wave = 32i x 128j.
// grid (32 jt, 32 it, 4 b) x 256.
// ---------------------------------------------------------------------------
__global__ __launch_bounds__(256) void k_energy(
        const unsigned short* __restrict__ qH, const unsigned short* __restrict__ qL,
        const unsigned short* __restrict__ kH, const unsigned short* __restrict__ kL,
        float* __restrict__ out) {
    int wave = threadIdx.x >> 6, lane = threadIdx.x & 63;
    int col = lane & 15, kg = lane >> 4;
    int jt = blockIdx.x, it = blockIdx.y, b = blockIdx.z;
    int i0w = it * 128 + wave * 32;
    int j0 = jt * 128;
    size_t base = (size_t)b * S;

    // Q fragments (B-operand): lane holds Q[i = i0w+iu*16+col][k-slice]
    s16x8 qbh[2][2], qbl[2][2];
    #pragma unroll
    for (int iu = 0; iu < 2; iu++) {
        size_t ro = (base + i0w + iu * 16 + col) * (size_t)D + kg * 8;
        #pragma unroll
        for (int kh2 = 0; kh2 < 2; kh2++) {
            qbh[iu][kh2] = *(const s16x8*)(qH + ro + kh2 * 32);
            qbl[iu][kh2] = *(const s16x8*)(qL + ro + kh2 * 32);
        }
    }

    f32x4 acc[2][8];
    #pragma unroll
    for (int iu = 0; iu < 2; iu++)
        #pragma unroll
        for (int ju = 0; ju < 8; ju++) acc[iu][ju] = (f32x4)0.f;

    #pragma unroll
    for (int ju = 0; ju < 8; ju++) {
        size_t ro = (base + j0 + ju * 16 + col) * (size_t)D + kg * 8;
        s16x8 kf0 = *(const s16x8*)(kH + ro);
        s16x8 kf1 = *(const s16x8*)(kH + ro + 32);
        s16x8 kl0 = *(const s16x8*)(kL + ro);
        s16x8 kl1 = *(const s16x8*)(kL + ro + 32);
        #pragma unroll
        for (int iu = 0; iu < 2; iu++) {
            f32x4 a = acc[iu][ju];
            a = __builtin_amdgcn_mfma_f32_16x16x32_bf16(kf0, qbh[iu][0], a, 0, 0, 0);
            a = __builtin_amdgcn_mfma_f32_16x16x32_bf16(kf1, qbh[iu][1], a, 0, 0, 0);
            a = __builtin_amdgcn_mfma_f32_16x16x32_bf16(kf0, qbl[iu][0], a, 0, 0, 0);
            a = __builtin_amdgcn_mfma_f32_16x16x32_bf16(kf1, qbl[iu][1], a, 0, 0, 0);
            a = __builtin_amdgcn_mfma_f32_16x16x32_bf16(kl0, qbh[iu][0], a, 0, 0, 0);
            a = __builtin_amdgcn_mfma_f32_16x16x32_bf16(kl1, qbh[iu][1], a, 0, 0, 0);
            acc[iu][ju] = a;
        }
    }

    #pragma unroll
    for (int iu = 0; iu < 2; iu++) {
        int i = i0w + iu * 16 + col;
        #pragma unroll
        for (int ju = 0; ju < 8; ju++) {
            int jb = j0 + ju * 16 + kg * 4;
            float di = (float)(i - jb);
            f32x4 v = acc[iu][ju];
            v.x *= __builtin_amdgcn_rcpf(fmaxf(fabsf(di), 1.0f));
            v.y *= __builtin_amdgcn_rcpf(fmaxf(fabsf(di - 1.0f), 1.0f));
            v.z *= __builtin_amdgcn_rcpf(fmaxf(fabsf(di - 2.0f), 1.0f));
            v.w *= __builtin_amdgcn_rcpf(fmaxf(fabsf(di - 3.0f), 1.0f));
            *(f32x4*)(out + (base + i) * (size_t)S + jb) = v;
        }
    }
}

// ---------------------------------------------------------------------------
extern "C" void kernel_launch(void* const* d_in, const int* in_sizes, int n_in,
                              void* d_out, int out_size, void* d_ws, size_t ws_size,
                              hipStream_t stream) {
    const float* feat = (const float*)d_in[0];
    const float* Wq   = (const float*)d_in[1];
    const float* Wk   = (const float*)d_in[2];
    const float* wc   = (const float*)d_in[3];
    const float* bc   = (const float*)d_in[4];
    const float* ls   = (const float*)d_in[5];
    float* out = (float*)d_out;

    char* ws = (char*)d_ws;
    unsigned short* wtH = (unsigned short*)ws;  ws += (size_t)128 * F * 2;
    unsigned short* wtL = (unsigned short*)ws;  ws += (size_t)128 * F * 2;
    unsigned short* qH  = (unsigned short*)ws;  ws += (size_t)NROW * D * 2;
    unsigned short* qL  = (unsigned short*)ws;  ws += (size_t)NROW * D * 2;
    unsigned short* kH  = (unsigned short*)ws;  ws += (size_t)NROW * D * 2;
    unsigned short* kL  = (unsigned short*)ws;  ws += (size_t)NROW * D * 2;

    hipLaunchKernelGGL(k_wt, dim3(64), dim3(256), 0, stream, Wq, Wk, wtH, wtL);
    hipLaunchKernelGGL(k_qk2, dim3(NROW / 16), dim3(256), 0, stream,
                       feat, wtH, wtL, wc, bc, ls, qH, qL, kH, kL);
    hipLaunchKernelGGL(k_energy, dim3(S / 128, S / 128, BB), dim3(256), 0, stream,
                       qH, qL, kH, kL, out);
}